// Round 8
// baseline (65.879 us; speedup 1.0000x reference)
//
#include <hip/hip_runtime.h>
#include <math.h>

namespace {

constexpr int Bn = 2, Hn = 128, Wn = 128, Cn = 256, Vn = 64;

__device__ __forceinline__ void load8(float* r, const float* p) {
    float4 a = *(const float4*)(p);
    float4 b = *(const float4*)(p + 4);
    r[0]=a.x; r[1]=a.y; r[2]=a.z; r[3]=a.w;
    r[4]=b.x; r[5]=b.y; r[6]=b.z; r[7]=b.w;
}

// 256 thr = 16 pixels x 16 channel-splits, 1 pixel/lane (R4 base). R7 change:
// FULLY UNROLLED di + flat softmax (no online rescale). Rationale: VGPR 72
// and 128 are the same occupancy bin (waves/CU halves at 64/128/256), so R4's
// rolled-di online softmax bought nothing in occupancy while serializing the
// 5 rows into dependent {load->4-deep-shfl-reduce->exp->rescale} chains. Flat
// form exposes 50 independent load8s + 25 independent accumulator chains for
// the scheduler to overlap. Everything stays exec-mask predicated (R6 showed
// scalar-branch fast/slow paths destroy load clustering). Target VGPR <=128.
__global__ __launch_bounds__(256)
void local_attn_kernel(const float* __restrict__ mainp,
                       const float* __restrict__ mainv,
                       const float* __restrict__ refp,
                       const float* __restrict__ refv,
                       float* __restrict__ outp)
{
    const int t = threadIdx.x;
    const int s = t & 15;       // channel/value split 0..15
    const int p = t >> 4;       // pixel 0..15
    const int blk = blockIdx.x; // 0 .. 2047
    const int seg = blk & 7;
    const int h   = (blk >> 3) & (Hn - 1);
    const int b   = blk >> 10;
    const int w   = seg * 16 + p;
    const int rowbase = b * Hn + h;

    // this lane's 16 main channels: s*8..s*8+7 and 128+s*8..128+s*8+7
    float m[16];
    const float* mp = mainp + ((size_t)rowbase * Wn + w) * Cn + s * 8;
    load8(m,     mp);
    load8(m + 8, mp + 128);

    // self score: full dot via 4-step shuffle reduce over the s lane bits
    float self = 0.f;
    #pragma unroll
    for (int c = 0; c < 16; ++c) self = fmaf(m[c], m[c], self);
    self += __shfl_xor(self, 1);
    self += __shfl_xor(self, 2);
    self += __shfl_xor(self, 4);
    self += __shfl_xor(self, 8);

    // ---------------- score phase: all 25 slots, fully unrolled ------------
    float sc[25];
    #pragma unroll
    for (int di = 0; di < 5; ++di) {
        const int hh = h + di - 2;
        const bool rowok = (unsigned)hh < (unsigned)Hn;
        const float* rp = refp + (size_t)(b * Hn + (rowok ? hh : 0)) * Wn * Cn + s * 8;
        #pragma unroll
        for (int dj = 0; dj < 5; ++dj) {
            const int col = w - 2 + dj;
            const bool ok = rowok && (unsigned)col < (unsigned)Wn;
            float r[8];
            #pragma unroll
            for (int c = 0; c < 8; ++c) r[c] = 0.f;
            if (ok) load8(r, rp + (size_t)col * Cn);
            float a = 0.f;
            #pragma unroll
            for (int c = 0; c < 8; ++c) a = fmaf(m[c], r[c], a);
            sc[di * 5 + dj] = a;
        }
    }
    #pragma unroll
    for (int di = 0; di < 5; ++di) {
        const int hh = h + di - 2;
        const bool rowok = (unsigned)hh < (unsigned)Hn;
        const float* rp = refp + (size_t)(b * Hn + (rowok ? hh : 0)) * Wn * Cn + s * 8;
        #pragma unroll
        for (int dj = 0; dj < 5; ++dj) {
            const int col = w - 2 + dj;
            const bool ok = rowok && (unsigned)col < (unsigned)Wn;
            float r[8];
            #pragma unroll
            for (int c = 0; c < 8; ++c) r[c] = 0.f;
            if (ok) load8(r, rp + (size_t)col * Cn + 128);
            float a = sc[di * 5 + dj];
            #pragma unroll
            for (int c = 0; c < 8; ++c) a = fmaf(m[8 + c], r[c], a);
            sc[di * 5 + dj] = a;
        }
    }

    // reduce all 25 slots across the 16 split lanes (lane bits 0..3)
    #pragma unroll
    for (int k = 0; k < 25; ++k) {
        float v = sc[k];
        v += __shfl_xor(v, 1);
        v += __shfl_xor(v, 2);
        v += __shfl_xor(v, 4);
        v += __shfl_xor(v, 8);
        sc[k] = v;
    }

    // ---------------- softmax over 26 (self is the last slot) --------------
    float mx = self;
    #pragma unroll
    for (int k = 0; k < 25; ++k) mx = fmaxf(mx, sc[k]);
    float den = __expf(self - mx);
    const float wself = den;
    #pragma unroll
    for (int k = 0; k < 25; ++k) { sc[k] = __expf(sc[k] - mx); den += sc[k]; }
    const float inv = 1.f / den;

    // ---------------- value phase (lane owns V channels s*4..s*4+3) --------
    float acc[4];
    {
        const float* mvp = mainv + ((size_t)rowbase * Wn + w) * Vn + s * 4;
        float4 a = *(const float4*)(mvp);
        acc[0] = wself * a.x; acc[1] = wself * a.y;
        acc[2] = wself * a.z; acc[3] = wself * a.w;
    }
    #pragma unroll
    for (int di = 0; di < 5; ++di) {
        const int hh = h + di - 2;
        const bool rowok = (unsigned)hh < (unsigned)Hn;
        const float* rvp = refv + (size_t)(b * Hn + (rowok ? hh : 0)) * Wn * Vn + s * 4;
        #pragma unroll
        for (int dj = 0; dj < 5; ++dj) {
            const int col = w - 2 + dj;
            float4 rv = make_float4(0.f, 0.f, 0.f, 0.f);
            if (rowok && (unsigned)col < (unsigned)Wn)
                rv = *(const float4*)(rvp + (size_t)col * Vn);
            const float wkj = sc[di * 5 + dj];
            acc[0] = fmaf(wkj, rv.x, acc[0]);
            acc[1] = fmaf(wkj, rv.y, acc[1]);
            acc[2] = fmaf(wkj, rv.z, acc[2]);
            acc[3] = fmaf(wkj, rv.w, acc[3]);
        }
    }

    float* op = outp + ((size_t)rowbase * Wn + w) * Vn + s * 4;
    float4 o;
    o.x = acc[0]*inv; o.y = acc[1]*inv; o.z = acc[2]*inv; o.w = acc[3]*inv;
    *(float4*)op = o;
}

} // namespace

extern "C" void kernel_launch(void* const* d_in, const int* in_sizes, int n_in,
                              void* d_out, int out_size, void* d_ws, size_t ws_size,
                              hipStream_t stream)
{
    const float* mainp = (const float*)d_in[0];
    const float* mainv = (const float*)d_in[1];
    const float* refp  = (const float*)d_in[2];
    const float* refv  = (const float*)d_in[3];
    float* outp = (float*)d_out;

    dim3 grid(Bn * Hn * 8);   // 2048 blocks: one per 16-pixel row segment
    dim3 block(256);          // 16 pixels x 16 splits
    hipLaunchKernelGGL(local_attn_kernel, grid, block, 0, stream,
                       mainp, mainv, refp, refv, outp);
}

// Round 9
// 46.976 us; speedup vs baseline: 1.4024x; 1.4024x over previous
//
#include <hip/hip_runtime.h>
#include <math.h>

namespace {

constexpr int Bn = 2, Hn = 128, Wn = 128, Cn = 256, Vn = 64;

__device__ __forceinline__ void load8(float* r, const float* p) {
    float4 a = *(const float4*)(p);
    float4 b = *(const float4*)(p + 4);
    r[0]=a.x; r[1]=a.y; r[2]=a.z; r[3]=a.w;
    r[4]=b.x; r[5]=b.y; r[6]=b.z; r[7]=b.w;
}

// 256 thr = 8 pixels x 32 channel-splits, 1 pixel/lane. R8 change vs R4:
// 32 splits (lane owns 8 of C=256, 2 of V=64) to push VGPR under the 64-reg
// occupancy cliff (waves/SIMD halve at VGPR bins 64/128/256; R4's 72 VGPR
// bought 4/SIMD, <=64 buys 8/SIMD). Grid 4096 blocks = 16384 waves, 2x R4.
// Same proven skeleton: rolled di, online softmax seeded by the self slot,
// exec-mask predication for OOB (no scalar branches - R6 lesson), no forced
// launch bounds (R2 lesson), wave = 2 px x 32 splits so all reduces are
// intra-wave shfl_xor over lane bits 0..4.
__global__ __launch_bounds__(256)
void local_attn_kernel(const float* __restrict__ mainp,
                       const float* __restrict__ mainv,
                       const float* __restrict__ refp,
                       const float* __restrict__ refv,
                       float* __restrict__ outp)
{
    const int t = threadIdx.x;
    const int s = t & 31;       // channel split 0..31 (8 ch each)
    const int p = t >> 5;       // pixel 0..7
    const int blk = blockIdx.x; // 0 .. 4095
    const int seg = blk & 15;
    const int h   = (blk >> 4) & (Hn - 1);
    const int b   = blk >> 11;
    const int w   = seg * 8 + p;
    const int rowbase = b * Hn + h;

    // this lane's 8 main channels: s*8 .. s*8+7
    float m[8];
    const float* mp = mainp + ((size_t)rowbase * Wn + w) * Cn + s * 8;
    load8(m, mp);

    // self score (slot 25): full dot via 5-step shuffle reduce over s bits
    float self = 0.f;
    #pragma unroll
    for (int c = 0; c < 8; ++c) self = fmaf(m[c], m[c], self);
    self += __shfl_xor(self, 1);
    self += __shfl_xor(self, 2);
    self += __shfl_xor(self, 4);
    self += __shfl_xor(self, 8);
    self += __shfl_xor(self, 16);

    // online-softmax state seeded with the self slot (weight exp(0)=1)
    float mx = self, den = 1.f;
    float acc0, acc1;
    {
        const float* mvp = mainv + ((size_t)rowbase * Wn + w) * Vn + s * 2;
        float2 a = *(const float2*)(mvp);
        acc0 = a.x; acc1 = a.y;
    }

    #pragma unroll 1
    for (int di = 0; di < 5; ++di) {
        const int hh = h + di - 2;
        const bool rowok = (unsigned)hh < (unsigned)Hn;
        const size_t rbase = (size_t)(b * Hn + (rowok ? hh : 0)) * Wn;
        const float* rp = refp + rbase * Cn + s * 8;

        // ---- scores for this di row (zero for padded slots, like reference)
        float sc[5];
        #pragma unroll
        for (int dj = 0; dj < 5; ++dj) {
            const int col = w - 2 + dj;
            const bool ok = rowok && (unsigned)col < (unsigned)Wn;
            float r[8];
            #pragma unroll
            for (int c = 0; c < 8; ++c) r[c] = 0.f;
            if (ok) load8(r, rp + (size_t)col * Cn);
            float a = 0.f;
            #pragma unroll
            for (int c = 0; c < 8; ++c) a = fmaf(m[c], r[c], a);
            sc[dj] = a;
        }

        // reduce partial dots across the 32 split lanes (lane bits 0..4)
        #pragma unroll
        for (int k = 0; k < 5; ++k) {
            float v = sc[k];
            v += __shfl_xor(v, 1);
            v += __shfl_xor(v, 2);
            v += __shfl_xor(v, 4);
            v += __shfl_xor(v, 8);
            v += __shfl_xor(v, 16);
            sc[k] = v;
        }

        // ---- online softmax row update
        const float rm = fmaxf(fmaxf(fmaxf(sc[0], sc[1]), fmaxf(sc[2], sc[3])), sc[4]);
        const float nm = fmaxf(mx, rm);
        const float e  = __expf(mx - nm);
        float wk[5];
        float sum = 0.f;
        #pragma unroll
        for (int k = 0; k < 5; ++k) { wk[k] = __expf(sc[k] - nm); sum += wk[k]; }
        den = den * e + sum;
        acc0 *= e; acc1 *= e;
        mx = nm;

        // ---- fused value row (lane owns V channels s*2, s*2+1)
        const float* rvp = refv + rbase * Vn + s * 2;
        #pragma unroll
        for (int dj = 0; dj < 5; ++dj) {
            const int col = w - 2 + dj;
            float2 rv = make_float2(0.f, 0.f);
            if (rowok && (unsigned)col < (unsigned)Wn)
                rv = *(const float2*)(rvp + (size_t)col * Vn);
            acc0 = fmaf(wk[dj], rv.x, acc0);
            acc1 = fmaf(wk[dj], rv.y, acc1);
        }
    }

    const float inv = 1.f / den;
    float* op = outp + ((size_t)rowbase * Wn + w) * Vn + s * 2;
    float2 o;
    o.x = acc0 * inv; o.y = acc1 * inv;
    *(float2*)op = o;
}

} // namespace

extern "C" void kernel_launch(void* const* d_in, const int* in_sizes, int n_in,
                              void* d_out, int out_size, void* d_ws, size_t ws_size,
                              hipStream_t stream)
{
    const float* mainp = (const float*)d_in[0];
    const float* mainv = (const float*)d_in[1];
    const float* refp  = (const float*)d_in[2];
    const float* refv  = (const float*)d_in[3];
    float* outp = (float*)d_out;

    dim3 grid(Bn * Hn * 16);  // 4096 blocks: one per 8-pixel row segment
    dim3 block(256);          // 8 pixels x 32 splits
    hipLaunchKernelGGL(local_attn_kernel, grid, block, 0, stream,
                       mainp, mainv, refp, refv, outp);
}

// Round 10
// 39.348 us; speedup vs baseline: 1.6743x; 1.1939x over previous
//
#include <hip/hip_runtime.h>
#include <math.h>

namespace {

constexpr int Bn = 2, Hn = 128, Wn = 128, Cn = 256, Vn = 64;

__device__ __forceinline__ void load8(float* r, const float* p) {
    float4 a = *(const float4*)(p);
    float4 b = *(const float4*)(p + 4);
    r[0]=a.x; r[1]=a.y; r[2]=a.z; r[3]=a.w;
    r[4]=b.x; r[5]=b.y; r[6]=b.z; r[7]=b.w;
}

// 256 thr = 8 pixel-PAIRS x 32 channel-splits; lane owns 2 adjacent px x 8ch.
// Synthesis of R4/R5/R8 evidence:
//  - pairing shares the 6 window columns between 2 px: score bytes/px
//    25KB->15KB, value 6.4->3.8KB (L1 path was the R4 bottleneck);
//  - 32 splits keep per-lane state small (m=16 regs not 32; R5's 92-VGPR
//    pairing was at 16 splits) targeting the <=64 VGPR occupancy bin;
//  - grid 2048 = 8 segs/row keeps the XCD round-robin halo-friendly (R5's
//    1024-block grid broke h-locality per XCD -> 3x FETCH);
//  - rolled di + online softmax (R4 skeleton), exec-mask predication only
//    (R6: scalar fast/slow branches destroy load clustering), no forced
//    launch bounds (R2: allocator spill disaster).
__global__ __launch_bounds__(256)
void local_attn_kernel(const float* __restrict__ mainp,
                       const float* __restrict__ mainv,
                       const float* __restrict__ refp,
                       const float* __restrict__ refv,
                       float* __restrict__ outp)
{
    const int t = threadIdx.x;
    const int s = t & 31;       // channel split 0..31 (8 ch each)
    const int g = t >> 5;       // pixel-pair 0..7
    const int blk = blockIdx.x; // 0 .. 2047
    const int seg = blk & 7;
    const int h   = (blk >> 3) & (Hn - 1);
    const int b   = blk >> 10;
    const int w0  = seg * 16 + g * 2;   // px0 = w0, px1 = w0+1
    const int rowbase = b * Hn + h;

    // main channels: 8 each for px0/px1 (ch = s*8 .. s*8+7)
    float m0[8], m1[8];
    const float* mp = mainp + ((size_t)rowbase * Wn + w0) * Cn + s * 8;
    load8(m0, mp);
    load8(m1, mp + Cn);

    // self scores (slot 25): full dot via 5-step shuffle reduce over s bits
    float self0 = 0.f, self1 = 0.f;
    #pragma unroll
    for (int c = 0; c < 8; ++c) {
        self0 = fmaf(m0[c], m0[c], self0);
        self1 = fmaf(m1[c], m1[c], self1);
    }
    #pragma unroll
    for (int k = 1; k < 32; k <<= 1) {
        self0 += __shfl_xor(self0, k);
        self1 += __shfl_xor(self1, k);
    }

    // online-softmax state seeded with the self slot (weight exp(0)=1)
    float mx0 = self0, mx1 = self1, den0 = 1.f, den1 = 1.f;
    float acc0[2], acc1[2];
    {
        const float* mvp = mainv + ((size_t)rowbase * Wn + w0) * Vn + s * 2;
        float2 a = *(const float2*)(mvp);
        float2 c = *(const float2*)(mvp + Vn);
        acc0[0] = a.x; acc0[1] = a.y;
        acc1[0] = c.x; acc1[1] = c.y;
    }

    #pragma unroll 1
    for (int di = 0; di < 5; ++di) {
        const int hh = h + di - 2;
        const bool rowok = (unsigned)hh < (unsigned)Hn;
        const size_t rbase = (size_t)(b * Hn + (rowok ? hh : 0)) * Wn;
        const float* rp = refp + rbase * Cn + s * 8;

        // ---- scores: 6 shared column loads serve both pixels ----
        float sc0[5], sc1[5];
        #pragma unroll
        for (int o = 0; o < 6; ++o) {
            const int col = w0 - 2 + o;
            const bool ok = rowok && (unsigned)col < (unsigned)Wn;
            float r[8];
            #pragma unroll
            for (int c = 0; c < 8; ++c) r[c] = 0.f;
            if (ok) load8(r, rp + (size_t)col * Cn);
            if (o < 5) {
                float a = 0.f;
                #pragma unroll
                for (int c = 0; c < 8; ++c) a = fmaf(m0[c], r[c], a);
                sc0[o] = a;
            }
            if (o >= 1) {
                float a = 0.f;
                #pragma unroll
                for (int c = 0; c < 8; ++c) a = fmaf(m1[c], r[c], a);
                sc1[o - 1] = a;
            }
        }

        // reduce partial dots across the 32 split lanes (lane bits 0..4)
        #pragma unroll
        for (int k = 0; k < 5; ++k) {
            float v0 = sc0[k], v1 = sc1[k];
            v0 += __shfl_xor(v0, 1);  v1 += __shfl_xor(v1, 1);
            v0 += __shfl_xor(v0, 2);  v1 += __shfl_xor(v1, 2);
            v0 += __shfl_xor(v0, 4);  v1 += __shfl_xor(v1, 4);
            v0 += __shfl_xor(v0, 8);  v1 += __shfl_xor(v1, 8);
            v0 += __shfl_xor(v0, 16); v1 += __shfl_xor(v1, 16);
            sc0[k] = v0; sc1[k] = v1;
        }

        // ---- online softmax row update (both pixels)
        const float rm0 = fmaxf(fmaxf(fmaxf(sc0[0], sc0[1]), fmaxf(sc0[2], sc0[3])), sc0[4]);
        const float rm1 = fmaxf(fmaxf(fmaxf(sc1[0], sc1[1]), fmaxf(sc1[2], sc1[3])), sc1[4]);
        const float nm0 = fmaxf(mx0, rm0), nm1 = fmaxf(mx1, rm1);
        const float e0 = __expf(mx0 - nm0), e1 = __expf(mx1 - nm1);
        float sum0 = 0.f, sum1 = 0.f;
        #pragma unroll
        for (int k = 0; k < 5; ++k) {
            sc0[k] = __expf(sc0[k] - nm0); sum0 += sc0[k];
            sc1[k] = __expf(sc1[k] - nm1); sum1 += sc1[k];
        }
        den0 = den0 * e0 + sum0;
        den1 = den1 * e1 + sum1;
        acc0[0] *= e0; acc0[1] *= e0;
        acc1[0] *= e1; acc1[1] *= e1;
        mx0 = nm0; mx1 = nm1;

        // ---- values: 6 shared float2 column loads serve both pixels ----
        const float* rvp = refv + rbase * Vn + s * 2;
        #pragma unroll
        for (int o = 0; o < 6; ++o) {
            const int col = w0 - 2 + o;
            float2 rv = make_float2(0.f, 0.f);
            if (rowok && (unsigned)col < (unsigned)Wn)
                rv = *(const float2*)(rvp + (size_t)col * Vn);
            if (o < 5) {
                const float wkj = sc0[o];
                acc0[0] = fmaf(wkj, rv.x, acc0[0]);
                acc0[1] = fmaf(wkj, rv.y, acc0[1]);
            }
            if (o >= 1) {
                const float wkj = sc1[o - 1];
                acc1[0] = fmaf(wkj, rv.x, acc1[0]);
                acc1[1] = fmaf(wkj, rv.y, acc1[1]);
            }
        }
    }

    const float inv0 = 1.f / den0, inv1 = 1.f / den1;
    float* op = outp + ((size_t)rowbase * Wn + w0) * Vn + s * 2;
    float2 o0, o1;
    o0.x = acc0[0] * inv0; o0.y = acc0[1] * inv0;
    o1.x = acc1[0] * inv1; o1.y = acc1[1] * inv1;
    *(float2*)(op)      = o0;
    *(float2*)(op + Vn) = o1;
}

} // namespace

extern "C" void kernel_launch(void* const* d_in, const int* in_sizes, int n_in,
                              void* d_out, int out_size, void* d_ws, size_t ws_size,
                              hipStream_t stream)
{
    const float* mainp = (const float*)d_in[0];
    const float* mainv = (const float*)d_in[1];
    const float* refp  = (const float*)d_in[2];
    const float* refv  = (const float*)d_in[3];
    float* outp = (float*)d_out;

    dim3 grid(Bn * Hn * 8);   // 2048 blocks: one per 16-pixel row segment
    dim3 block(256);          // 8 pairs x 32 splits
    hipLaunchKernelGGL(local_attn_kernel, grid, block, 0, stream,
                       mainp, mainv, refp, refv, outp);
}

// Round 12
// 35.518 us; speedup vs baseline: 1.8548x; 1.1078x over previous
//
#include <hip/hip_runtime.h>
#include <math.h>

namespace {

constexpr int Bn = 2, Hn = 128, Wn = 128, Cn = 256, Vn = 64;

__device__ __forceinline__ void load8(float* r, const float* p) {
    float4 a = *(const float4*)(p);
    float4 b = *(const float4*)(p + 4);
    r[0]=a.x; r[1]=a.y; r[2]=a.z; r[3]=a.w;
    r[4]=b.x; r[5]=b.y; r[6]=b.z; r[7]=b.w;
}

// DPP-based add of a row-permuted copy: executes on the VALU pipe, not the
// DS pipe. CTRL must be a compile-time constant (builtin requirement), hence
// the template parameter. 0xB1=quad_perm(1,0,3,2)=xor1, 0x4E=quad_perm
// (2,3,0,1)=xor2, 0x124=row_ror:4, 0x128=row_ror:8 (rotations are fine for
// full-row sums).
template <int CTRL>
__device__ __forceinline__ float row_add(float v) {
    int sh = __builtin_amdgcn_update_dpp(0, __float_as_int(v), CTRL, 0xF, 0xF, true);
    return v + __int_as_float(sh);
}

// Sum over the 32 split lanes (lane bits 0..4), result in all lanes.
// 4 DPP adds (VALU pipe) + ONE ds_swizzle xor16 (DS pipe) instead of 5 DS
// shuffles: cuts DS-pipe ops 5x in the reduction.
__device__ __forceinline__ float split_reduce(float v) {
    v = row_add<0xB1>(v);    // xor1
    v = row_add<0x4E>(v);    // xor2
    v = row_add<0x124>(v);   // +ror4 } full 16-lane row sum
    v = row_add<0x128>(v);   // +ror8 }
    v += __int_as_float(__builtin_amdgcn_ds_swizzle(__float_as_int(v), 0x401F)); // xor16
    return v;
}

// 256 thr = 8 pixel-PAIRS x 32 channel-splits; lane owns 2 adjacent px x 8ch.
// R9 structure (best: 39.3us, VGPR 56) with ONE change: the 5-step shfl_xor
// reduces (50 DS-pipe ops per di) are replaced by DPP-rotation reduces
// (VALU) + a single ds_swizzle xor16 per value (10 DS ops per di). R9
// accounting: ~260 DS ops/lane x 5.8cyc ~= 20us/CU of DS serialization.
__global__ __launch_bounds__(256)
void local_attn_kernel(const float* __restrict__ mainp,
                       const float* __restrict__ mainv,
                       const float* __restrict__ refp,
                       const float* __restrict__ refv,
                       float* __restrict__ outp)
{
    const int t = threadIdx.x;
    const int s = t & 31;       // channel split 0..31 (8 ch each)
    const int g = t >> 5;       // pixel-pair 0..7
    const int blk = blockIdx.x; // 0 .. 2047
    const int seg = blk & 7;
    const int h   = (blk >> 3) & (Hn - 1);
    const int b   = blk >> 10;
    const int w0  = seg * 16 + g * 2;   // px0 = w0, px1 = w0+1
    const int rowbase = b * Hn + h;

    // main channels: 8 each for px0/px1 (ch = s*8 .. s*8+7)
    float m0[8], m1[8];
    const float* mp = mainp + ((size_t)rowbase * Wn + w0) * Cn + s * 8;
    load8(m0, mp);
    load8(m1, mp + Cn);

    // self scores (slot 25)
    float self0 = 0.f, self1 = 0.f;
    #pragma unroll
    for (int c = 0; c < 8; ++c) {
        self0 = fmaf(m0[c], m0[c], self0);
        self1 = fmaf(m1[c], m1[c], self1);
    }
    self0 = split_reduce(self0);
    self1 = split_reduce(self1);

    // online-softmax state seeded with the self slot (weight exp(0)=1)
    float mx0 = self0, mx1 = self1, den0 = 1.f, den1 = 1.f;
    float acc0[2], acc1[2];
    {
        const float* mvp = mainv + ((size_t)rowbase * Wn + w0) * Vn + s * 2;
        float2 a = *(const float2*)(mvp);
        float2 c = *(const float2*)(mvp + Vn);
        acc0[0] = a.x; acc0[1] = a.y;
        acc1[0] = c.x; acc1[1] = c.y;
    }

    #pragma unroll 1
    for (int di = 0; di < 5; ++di) {
        const int hh = h + di - 2;
        const bool rowok = (unsigned)hh < (unsigned)Hn;
        const size_t rbase = (size_t)(b * Hn + (rowok ? hh : 0)) * Wn;
        const float* rp = refp + rbase * Cn + s * 8;

        // ---- scores: 6 shared column loads serve both pixels ----
        float sc0[5], sc1[5];
        #pragma unroll
        for (int o = 0; o < 6; ++o) {
            const int col = w0 - 2 + o;
            const bool ok = rowok && (unsigned)col < (unsigned)Wn;
            float r[8];
            #pragma unroll
            for (int c = 0; c < 8; ++c) r[c] = 0.f;
            if (ok) load8(r, rp + (size_t)col * Cn);
            if (o < 5) {
                float a = 0.f;
                #pragma unroll
                for (int c = 0; c < 8; ++c) a = fmaf(m0[c], r[c], a);
                sc0[o] = a;
            }
            if (o >= 1) {
                float a = 0.f;
                #pragma unroll
                for (int c = 0; c < 8; ++c) a = fmaf(m1[c], r[c], a);
                sc1[o - 1] = a;
            }
        }

        // reduce partial dots across the 32 split lanes
        #pragma unroll
        for (int k = 0; k < 5; ++k) {
            sc0[k] = split_reduce(sc0[k]);
            sc1[k] = split_reduce(sc1[k]);
        }

        // ---- online softmax row update (both pixels)
        const float rm0 = fmaxf(fmaxf(fmaxf(sc0[0], sc0[1]), fmaxf(sc0[2], sc0[3])), sc0[4]);
        const float rm1 = fmaxf(fmaxf(fmaxf(sc1[0], sc1[1]), fmaxf(sc1[2], sc1[3])), sc1[4]);
        const float nm0 = fmaxf(mx0, rm0), nm1 = fmaxf(mx1, rm1);
        const float e0 = __expf(mx0 - nm0), e1 = __expf(mx1 - nm1);
        float sum0 = 0.f, sum1 = 0.f;
        #pragma unroll
        for (int k = 0; k < 5; ++k) {
            sc0[k] = __expf(sc0[k] - nm0); sum0 += sc0[k];
            sc1[k] = __expf(sc1[k] - nm1); sum1 += sc1[k];
        }
        den0 = den0 * e0 + sum0;
        den1 = den1 * e1 + sum1;
        acc0[0] *= e0; acc0[1] *= e0;
        acc1[0] *= e1; acc1[1] *= e1;
        mx0 = nm0; mx1 = nm1;

        // ---- values: 6 shared float2 column loads serve both pixels ----
        const float* rvp = refv + rbase * Vn + s * 2;
        #pragma unroll
        for (int o = 0; o < 6; ++o) {
            const int col = w0 - 2 + o;
            float2 rv = make_float2(0.f, 0.f);
            if (rowok && (unsigned)col < (unsigned)Wn)
                rv = *(const float2*)(rvp + (size_t)col * Vn);
            if (o < 5) {
                const float wkj = sc0[o];
                acc0[0] = fmaf(wkj, rv.x, acc0[0]);
                acc0[1] = fmaf(wkj, rv.y, acc0[1]);
            }
            if (o >= 1) {
                const float wkj = sc1[o - 1];
                acc1[0] = fmaf(wkj, rv.x, acc1[0]);
                acc1[1] = fmaf(wkj, rv.y, acc1[1]);
            }
        }
    }

    const float inv0 = 1.f / den0, inv1 = 1.f / den1;
    float* op = outp + ((size_t)rowbase * Wn + w0) * Vn + s * 2;
    float2 o0, o1;
    o0.x = acc0[0] * inv0; o0.y = acc0[1] * inv0;
    o1.x = acc1[0] * inv1; o1.y = acc1[1] * inv1;
    *(float2*)(op)      = o0;
    *(float2*)(op + Vn) = o1;
}

} // namespace

extern "C" void kernel_launch(void* const* d_in, const int* in_sizes, int n_in,
                              void* d_out, int out_size, void* d_ws, size_t ws_size,
                              hipStream_t stream)
{
    const float* mainp = (const float*)d_in[0];
    const float* mainv = (const float*)d_in[1];
    const float* refp  = (const float*)d_in[2];
    const float* refv  = (const float*)d_in[3];
    float* outp = (float*)d_out;

    dim3 grid(Bn * Hn * 8);   // 2048 blocks: one per 16-pixel row segment
    dim3 block(256);          // 8 pairs x 32 splits
    hipLaunchKernelGGL(local_attn_kernel, grid, block, 0, stream,
                       mainp, mainv, refp, refv, outp);
}